// Round 1
// baseline (43.187 us; speedup 1.0000x reference)
//
#include <hip/hip_runtime.h>

// Conv2d 16->16, k=3, stride 1, pad 1, H=W=1024.
// Round 2: vectorized staging + swapped-operand MFMA for float4 stores.
//   GEMM view: D[px][co] = sum_k B[px][k] * A[k][co], k = tap*16 + ci, 10 taps
//   (tap 9 = zero pad so K=160 = 5 x mfma_f32_16x16x32_bf16 per 16-px group).
//   Staging: TH=8 tile -> halo = 10 rows x 72 aligned cols = 180 float4-jobs,
//   one per thread (tid<180): 16 x global_load_dwordx4 (4x MLP vs round 1's
//   scalar loads), clamp+mask instead of divergent bounds checks, LDS writes
//   as 8 x ds_write_b128 (conflict-free under the 2-bit XOR swizzle).
//   MFMA operands swapped (A=pixels, B=weights; wA layout unchanged): D row
//   becomes the pixel index -> each lane holds 4 consecutive pixels of one
//   c_out -> 16 global_store_dwordx4 instead of 64 scalar stores.
//   Grid 2048 blocks, ~5 resident/CU -> 2 generations so staging of one
//   block overlaps compute of another.

#define H 1024
#define W 1024
#define HW (H * W)
#define TW 64
#define TH 8
#define LROWS 10            // TH + 2 halo rows
#define LPITCH 2112         // 66 cols * 32 B (16 ci * 2 B)
#define LDS_BYTES (LROWS * LPITCH)   // 21120

typedef __bf16 bf16x8 __attribute__((ext_vector_type(8)));
typedef float f32x4 __attribute__((ext_vector_type(4)));
typedef unsigned short ushort8 __attribute__((ext_vector_type(8)));
typedef unsigned int uint4v __attribute__((ext_vector_type(4)));

__device__ __host__ inline unsigned short f2bf(float f) {
  unsigned u = __builtin_bit_cast(unsigned, f);
  return (unsigned short)((u + 0x7fffu + ((u >> 16) & 1u)) >> 16);  // RNE
}

// wA[p*512 + lane*8 + j]: B-fragment (weights), col=co=lane&15,
// k=(lane>>4)*8+j; mfma p covers taps {2p, 2p+1}; tap = 2p + (k>>4), ci=k&15.
// (Same layout as round 1's A fragment -- operand swap needs no prep change.)
__global__ __launch_bounds__(256) void conv_prep(const float* __restrict__ w,
                                                 unsigned short* __restrict__ wA) {
  int i = blockIdx.x * 256 + threadIdx.x;
  if (i >= 5 * 64 * 8) return;
  int j = i & 7;
  int l = (i >> 3) & 63;
  int p = i >> 9;
  int k = (l >> 4) * 8 + j;
  int t = 2 * p + (k >> 4);
  int ci = k & 15;
  int co = l & 15;
  float v = (t <= 8) ? w[co * 144 + ci * 9 + t] : 0.f;  // w[co][ci][ky][kx], t=ky*3+kx
  wA[i] = f2bf(v);
}

__global__ __launch_bounds__(256, 5) void conv_mfma(
    const float* __restrict__ x, const unsigned short* __restrict__ wA,
    float* __restrict__ out) {
  __shared__ __align__(16) char lds[LDS_BYTES];

  const int tid  = threadIdx.x;
  const int lane = tid & 63;
  const int wave = tid >> 6;
  const int m = lane & 15;   // A row = pixel within 16-px group; also D col = co
  const int q = lane >> 4;   // k-quarter
  const int colbase = blockIdx.x * TW;
  const int rowbase = blockIdx.y * TH;

  // ---- stage x tile: global [ci][y][x] fp32 -> LDS [y][x][ci] bf16 ----
  // 10 rows x 18 aligned float4-quads covering gx in [colbase-4, colbase+68).
  if (tid < 180) {
    const int ly  = tid / 18;          // 0..9
    const int qx  = tid - ly * 18;     // 0..17
    const int gy  = rowbase - 1 + ly;
    const int gx0 = colbase - 4 + 4 * qx;
    const bool rowok = (unsigned)gy < (unsigned)H;
    const int gyc  = gy < 0 ? 0 : (gy > H - 1 ? H - 1 : gy);
    const int gx0c = gx0 < 0 ? 0 : (gx0 > W - 4 ? W - 4 : gx0);
    const float* xb = x + gyc * W + gx0c;   // always valid, 16-B aligned

    float fm[4];      // 0/1 pad mask (image bounds)
    int lok[4];       // LDS col in [0,66)?
    int lb[4];        // un-swizzled LDS byte base of this col
    int swz[4];
#pragma unroll
    for (int i = 0; i < 4; ++i) {
      const int gx = gx0 + i;
      fm[i] = (rowok && (unsigned)gx < (unsigned)W) ? 1.f : 0.f;
      const int lx = gx - (colbase - 1);
      lok[i] = (unsigned)lx < 66u;
      lb[i]  = ly * LPITCH + lx * 32;
      swz[i] = ((lx >> 2) & 3) << 4;
    }
    // two halves of 8 channels each: 8 independent dwordx4 loads in flight,
    // then pack to bf16 and write one b128 per col (ci 8h..8h+7).
#pragma unroll
    for (int h = 0; h < 2; ++h) {
      f32x4 L[8];
#pragma unroll
      for (int c = 0; c < 8; ++c)
        L[c] = *(const f32x4*)(xb + (h * 8 + c) * HW);
#pragma unroll
      for (int i = 0; i < 4; ++i) {
        if (lok[i]) {
          uint4v d;
#pragma unroll
          for (int p = 0; p < 4; ++p) {
            const unsigned lo = f2bf(L[2 * p][i] * fm[i]);
            const unsigned hi = f2bf(L[2 * p + 1][i] * fm[i]);
            d[p] = lo | (hi << 16);
          }
          *(uint4v*)(lds + ((lb[i] + h * 16) ^ swz[i])) = d;
        }
      }
    }
  }

  // ---- B fragments (weights): 5 x 16B uniform cached loads ----
  ushort8 wU[5];
#pragma unroll
  for (int p = 0; p < 5; ++p)
    wU[p] = *(const ushort8*)&wA[(p * 64 + lane) * 8];

  // ---- per-lane A (pixel) base addresses (g/r-invariant under 2-bit swizzle)
  int baseaddr[5];
#pragma unroll
  for (int p = 0; p < 5; ++p) {
    int t = 2 * p + (q >> 1);
    int ky = 0, kx = 0;
    if (t <= 8) { ky = t / 3; kx = t - ky * 3; }  // t==9: valid addr, zero weights
    int col = m + kx;
    int b = ky * LPITCH + col * 32 + (q & 1) * 16;
    b ^= ((col >> 2) & 3) << 4;
    baseaddr[p] = b + wave * 2 * LPITCH;
  }

  __syncthreads();

  // ---- compute: wave handles rows wave*2..+1, 4 groups of 16 px per row ----
#pragma unroll
  for (int r = 0; r < 2; ++r) {
#pragma unroll
    for (int g = 0; g < 4; ++g) {
      f32x4 acc = {0.f, 0.f, 0.f, 0.f};
#pragma unroll
      for (int p = 0; p < 5; ++p) {
        ushort8 bU = *(const ushort8*)(lds + (baseaddr[p] + r * LPITCH + g * 512));
        acc = __builtin_amdgcn_mfma_f32_16x16x32_bf16(
            __builtin_bit_cast(bf16x8, bU),       // A = pixels
            __builtin_bit_cast(bf16x8, wU[p]),    // B = weights
            acc, 0, 0, 0);
      }
      // D: col = lane&15 = c_out, row = q*4+j = pixel  -> float4 store of 4
      // consecutive pixels for one channel.
      const int y  = rowbase + wave * 2 + r;
      const int x0 = colbase + g * 16 + q * 4;
      *(f32x4*)(out + m * HW + y * W + x0) = acc;
    }
  }
}

extern "C" void kernel_launch(void* const* d_in, const int* in_sizes, int n_in,
                              void* d_out, int out_size, void* d_ws, size_t ws_size,
                              hipStream_t stream) {
  const float* x = (const float*)d_in[0];            // (1,16,1024,1024) fp32
  const float* w = (const float*)d_in[1];            // (16,16,3,3) fp32
  float* out = (float*)d_out;                        // (16,1024,1024) fp32
  unsigned short* wA = (unsigned short*)d_ws;        // 2560 ushorts = 5120 B

  conv_prep<<<10, 256, 0, stream>>>(w, wA);

  dim3 grid(W / TW, H / TH);                         // 16 x 128 = 2048 blocks
  conv_mfma<<<grid, 256, 0, stream>>>(x, wA, out);
}